// Round 10
// baseline (210.023 us; speedup 1.0000x reference)
//
#include <hip/hip_runtime.h>
#include <hip/hip_bf16.h>

#define NLEAF 256
#define MBLK 128
#define THREADS 512

typedef __attribute__((ext_vector_type(4))) float f32x4;
typedef __attribute__((ext_vector_type(4))) unsigned int uint4v;
typedef __attribute__((ext_vector_type(8))) __bf16 bf16x8;
typedef __attribute__((ext_vector_type(4))) __bf16 bf16x4;

// LDS layout (bytes), per block = 76544 B -> 2 blocks/CU
#define OFF_DIST 0      // 65536: dist bf16 [256 leaves][128 perm-rows]; first 32KB doubles as x-stage
#define OFF_T    65536  // 8192 : tree ping-pong PA/PB
#define OFF_AC   73728  // 1024 : A_c[255]
#define OFF_BC   74752  // 1024 : B_c[255]
#define OFF_ANG  75776  // 512  : angles[128]
#define OFF_RAY  76288  // 256  : ray[64]
#define SMEM_BYTES 76544

__device__ __forceinline__ float sigf(float s) { return 1.0f / (1.0f + __expf(-s)); }

// dist row permutation: row r = rg[6:5] mt[4] g[3:2] e[1:0]  ->  p = rg g mt e
// so one ds_read_b128 at (rg*32+g*8) delivers [mt0 e0..3 | mt1 e0..3].
__device__ __forceinline__ int permr(int r) {
  return (r & 0x63) | ((r & 0x0C) << 1) | ((r & 0x10) >> 2);
}

// Pre-pass: T fp32 [l][k(64)][w(32)] -> bf16 ws in cg-major MFMA FRAGMENT ORDER:
// off(k,w) = (w>>4)*2048 + (k>>5)*1024 + (((k>>3)&3)*16 + (w&15))*16 + (k&7)*2
// so a wave (cg) reads leaf l's two fragments at l*4096 + cg*2048 + {0,1024} + lane*16.
__global__ __launch_bounds__(256) void prep_T(const float* __restrict__ T,
                                              __bf16* __restrict__ wsT) {
  __shared__ char tile[4096];
  const int l = blockIdx.x;
  const float* src = T + (size_t)l * 2048;
  const int t = threadIdx.x;
#pragma unroll
  for (int p = 0; p < 2; ++p) {
    int e = p * 1024 + t * 4;  // element within leaf: k = e>>5, w = e&31
    f32x4 v = *(const f32x4*)(src + e);
    int k = e >> 5, w0 = e & 31;
#pragma unroll
    for (int j = 0; j < 4; ++j) {
      int w = w0 + j;
      int off = (w >> 4) * 2048 + (k >> 5) * 1024 +
                (((k >> 3) & 3) * 16 + (w & 15)) * 16 + (k & 7) * 2;
      *(__bf16*)(tile + off) = (__bf16)v[j];
    }
  }
  __syncthreads();
  *(uint4v*)((char*)wsT + (size_t)l * 4096 + t * 16) = *(const uint4v*)(tile + t * 16);
}

template <bool USE_WS>
__global__ __launch_bounds__(THREADS, 4)
void prl_main(const float* __restrict__ x, const float* __restrict__ ray,
              const float* __restrict__ w_i, const float* __restrict__ b_i,
              const float* __restrict__ a_i, const void* __restrict__ tsrc,
              float* __restrict__ out) {
  extern __shared__ char smem[];
  const int tid = threadIdx.x;
  const int lane = tid & 63;
  const int wid = tid >> 6;
  const int rg = wid >> 1;   // row-group: 32 rows
  const int cg = wid & 1;    // col-group: 16 cols
  const int g = lane >> 4;
  const int ln = lane & 15;
  const int row0 = blockIdx.x * MBLK;

  float* A_c = (float*)(smem + OFF_AC);
  float* B_c = (float*)(smem + OFF_BC);
  float* angles = (float*)(smem + OFF_ANG);
  float* ray_l = (float*)(smem + OFF_RAY);
  __bf16* distb = (__bf16*)(smem + OFF_DIST);

  // ---- stage node constants + ray ----
  if (tid < 255) {
    float aa = 1.0f + a_i[tid];
    A_c[tid] = (0.5f + sigf(w_i[tid])) * aa;
    B_c[tid] = -sigf(b_i[tid]) * aa;
  }
  if (tid >= 256 && tid < 320) ray_l[tid - 256] = ray[tid - 256];
  __syncthreads();

  // ---- ray norm (row-invariant): one 16-lane-group reduce, hoisted ----
  float rn;
  {
    f32x4 rv = *(const f32x4*)(ray_l + (tid & 15) * 4);
    float a2 = rv[0] * rv[0] + rv[1] * rv[1] + rv[2] * rv[2] + rv[3] * rv[3];
#pragma unroll
    for (int s = 1; s < 16; s <<= 1) a2 += __shfl_xor(a2, s, 64);
    rn = fmaxf(sqrtf(a2), 1e-8f);
  }

  // ---- x staging (128 rows = 32KB in dist region), angles ----
  float* xp = (float*)(smem + OFF_DIST);
  {
    const float* xg = x + (size_t)row0 * 64;
#pragma unroll
    for (int p = 0; p < 4; ++p) {
      int idx = p * 512 + tid;  // float4 slot 0..2047
      f32x4 v = *(const f32x4*)(xg + idx * 4);
      *(f32x4*)(xp + idx * 4) = v;
      int cgr = idx & 15;
      f32x4 rv = *(const f32x4*)(ray_l + cgr * 4);
      float a0 = v[0] * v[0] + v[1] * v[1] + v[2] * v[2] + v[3] * v[3];
      float a1 = v[0] * rv[0] + v[1] * rv[1] + v[2] * rv[2] + v[3] * rv[3];
#pragma unroll
      for (int s = 1; s < 16; s <<= 1) {
        a0 += __shfl_xor(a0, s, 64);
        a1 += __shfl_xor(a1, s, 64);
      }
      if ((tid & 15) == 0) {
        int r = idx >> 4;  // 0..127
        float xn = fmaxf(sqrtf(a0), 1e-8f);
        float cs = a1 / (xn * rn);
        cs = fminf(fmaxf(cs, -1.0f), 1.0f);
        angles[r] = acosf(cs) * 0.31830988618379067f;
      }
    }
  }
  __syncthreads();

  // ---- A-fragment extraction (each wave: its rg's 32 rows, both kt) ----
  bf16x8 afrag[2][2];
#pragma unroll
  for (int mt = 0; mt < 2; ++mt)
#pragma unroll
    for (int kt = 0; kt < 2; ++kt) {
      int rl = rg * 32 + mt * 16 + ln;
      int k0 = kt * 32 + g * 8;
      f32x4 u0 = *(const f32x4*)(xp + rl * 64 + k0);
      f32x4 u1 = *(const f32x4*)(xp + rl * 64 + k0 + 4);
      bf16x8 af;
      af[0] = (__bf16)u0[0]; af[1] = (__bf16)u0[1];
      af[2] = (__bf16)u0[2]; af[3] = (__bf16)u0[3];
      af[4] = (__bf16)u1[0]; af[5] = (__bf16)u1[1];
      af[6] = (__bf16)u1[2]; af[7] = (__bf16)u1[3];
      afrag[mt][kt] = af;
    }
  __syncthreads();  // x region free -> tree may overwrite with dist

  // ---- tree probabilities: ping-pong in OFF_T area (8KB), rows=128 ----
  __bf16* PA = (__bf16*)(smem + OFF_T);
  __bf16* PB = (__bf16*)(smem + OFF_T + 4096);
  if (tid < 128) {  // P0 -> P1 (2 x 128)
    float ang = angles[tid];
    float d = sigf(fmaf(A_c[0], ang, B_c[0]));
    PA[tid] = (__bf16)d;
    PA[128 + tid] = (__bf16)(1.0f - d);
  }
  __syncthreads();
  if (tid < 256) {  // P1 -> P2 (4 x 128)
    int n = tid >> 7, r = tid & 127;
    float p = (float)PA[tid];
    float ang = angles[r];
    float d = sigf(fmaf(A_c[1 + n], ang, B_c[1 + n]));
    PB[(2 * n) * 128 + r] = (__bf16)(p * d);
    PB[(2 * n + 1) * 128 + r] = (__bf16)(p * (1.0f - d));
  }
  __syncthreads();
  {  // P2 -> P3 (8 x 128)
    int n = tid >> 7, r = tid & 127;
    float p = (float)PB[tid];
    float ang = angles[r];
    float d = sigf(fmaf(A_c[3 + n], ang, B_c[3 + n]));
    PA[(2 * n) * 128 + r] = (__bf16)(p * d);
    PA[(2 * n + 1) * 128 + r] = (__bf16)(p * (1.0f - d));
  }
  __syncthreads();
#pragma unroll
  for (int it = 0; it < 2; ++it) {  // P3 -> P4 (16 x 128)
    int e = it * 512 + tid;
    int n = e >> 7, r = e & 127;
    float p = (float)PA[e];
    float ang = angles[r];
    float d = sigf(fmaf(A_c[7 + n], ang, B_c[7 + n]));
    PB[(2 * n) * 128 + r] = (__bf16)(p * d);
    PB[(2 * n + 1) * 128 + r] = (__bf16)(p * (1.0f - d));
  }
  __syncthreads();
  {  // P4 -> fused levels 4..7 -> dist [leaf][perm-row]
    const int r = tid & 127;
    const int pr = permr(r);
    const float ang = angles[r];
#pragma unroll
    for (int it = 0; it < 4; ++it) {
      int n4 = it * 4 + (tid >> 7);
      float p4 = (float)PB[n4 * 128 + r];
      float d4 = sigf(fmaf(A_c[15 + n4], ang, B_c[15 + n4]));
      float p5[2] = {p4 * d4, p4 * (1.0f - d4)};
#pragma unroll
      for (int b5 = 0; b5 < 2; ++b5) {
        int n5 = 2 * n4 + b5;
        float d5 = sigf(fmaf(A_c[31 + n5], ang, B_c[31 + n5]));
        float p6[2] = {p5[b5] * d5, p5[b5] * (1.0f - d5)};
#pragma unroll
        for (int b6 = 0; b6 < 2; ++b6) {
          int n6 = 2 * n5 + b6;
          float d6 = sigf(fmaf(A_c[63 + n6], ang, B_c[63 + n6]));
          float p7[2] = {p6[b6] * d6, p6[b6] * (1.0f - d6)};
#pragma unroll
          for (int b7 = 0; b7 < 2; ++b7) {
            int n7 = 2 * n6 + b7;
            float d7 = sigf(fmaf(A_c[127 + n7], ang, B_c[127 + n7]));
            float pv = p7[b7];
            distb[(2 * n7) * 128 + pr] = (__bf16)(pv * d7);
            distb[(2 * n7 + 1) * 128 + pr] = (__bf16)(pv * (1.0f - d7));
          }
        }
      }
    }
  }
  __syncthreads();  // dist visible; NO barriers from here on — waves free-run

  // ---- leaf loop: B direct global->VGPR, 8 named register sets,
  //      prefetch distance 7 compute-phases (~250 cyc), barrier-free ----
  f32x4 acc0 = {}, acc1 = {};
  const f32x4 zero = {0.0f, 0.0f, 0.0f, 0.0f};
  const char* dB = (const char*)distb + (rg * 32 + g * 8) * 2;

#define COMPUTE(BA, BB, DP)                                                        \
  {                                                                                \
    bf16x8 q = *(const bf16x8*)(DP);                                               \
    f32x4 dv0 = (f32x4){(float)q[0], (float)q[1], (float)q[2], (float)q[3]};       \
    f32x4 dv1 = (f32x4){(float)q[4], (float)q[5], (float)q[6], (float)q[7]};       \
    f32x4 y0 = __builtin_amdgcn_mfma_f32_16x16x32_bf16(afrag[0][0], BA, zero, 0, 0, 0); \
    y0 = __builtin_amdgcn_mfma_f32_16x16x32_bf16(afrag[0][1], BB, y0, 0, 0, 0);    \
    f32x4 y1 = __builtin_amdgcn_mfma_f32_16x16x32_bf16(afrag[1][0], BA, zero, 0, 0, 0); \
    y1 = __builtin_amdgcn_mfma_f32_16x16x32_bf16(afrag[1][1], BB, y1, 0, 0, 0);    \
    acc0 += dv0 * y0;                                                              \
    acc1 += dv1 * y1;                                                              \
  }

  if constexpr (USE_WS) {
    const char* tb = (const char*)tsrc;
    const unsigned int lo = cg * 2048 + lane * 16;
    unsigned int o0 = lo +     0, o1 = lo +  4096, o2 = lo +  8192, o3 = lo + 12288;
    unsigned int o4 = lo + 16384, o5 = lo + 20480, o6 = lo + 24576, o7 = lo + 28672;
    bf16x8 s0a = *(const bf16x8*)(tb + o0), s0b = *(const bf16x8*)(tb + o0 + 1024);
    bf16x8 s1a = *(const bf16x8*)(tb + o1), s1b = *(const bf16x8*)(tb + o1 + 1024);
    bf16x8 s2a = *(const bf16x8*)(tb + o2), s2b = *(const bf16x8*)(tb + o2 + 1024);
    bf16x8 s3a = *(const bf16x8*)(tb + o3), s3b = *(const bf16x8*)(tb + o3 + 1024);
    bf16x8 s4a = *(const bf16x8*)(tb + o4), s4b = *(const bf16x8*)(tb + o4 + 1024);
    bf16x8 s5a = *(const bf16x8*)(tb + o5), s5b = *(const bf16x8*)(tb + o5 + 1024);
    bf16x8 s6a = *(const bf16x8*)(tb + o6), s6b = *(const bf16x8*)(tb + o6 + 1024);
    bf16x8 s7a = *(const bf16x8*)(tb + o7), s7b = *(const bf16x8*)(tb + o7 + 1024);
    const char* dl = dB;
    for (int l8 = 0; l8 < NLEAF - 8; l8 += 8) {
      COMPUTE(s0a, s0b, dl + 0 * 256);
      o0 += 32768; s0a = *(const bf16x8*)(tb + o0); s0b = *(const bf16x8*)(tb + o0 + 1024);
      COMPUTE(s1a, s1b, dl + 1 * 256);
      o1 += 32768; s1a = *(const bf16x8*)(tb + o1); s1b = *(const bf16x8*)(tb + o1 + 1024);
      COMPUTE(s2a, s2b, dl + 2 * 256);
      o2 += 32768; s2a = *(const bf16x8*)(tb + o2); s2b = *(const bf16x8*)(tb + o2 + 1024);
      COMPUTE(s3a, s3b, dl + 3 * 256);
      o3 += 32768; s3a = *(const bf16x8*)(tb + o3); s3b = *(const bf16x8*)(tb + o3 + 1024);
      COMPUTE(s4a, s4b, dl + 4 * 256);
      o4 += 32768; s4a = *(const bf16x8*)(tb + o4); s4b = *(const bf16x8*)(tb + o4 + 1024);
      COMPUTE(s5a, s5b, dl + 5 * 256);
      o5 += 32768; s5a = *(const bf16x8*)(tb + o5); s5b = *(const bf16x8*)(tb + o5 + 1024);
      COMPUTE(s6a, s6b, dl + 6 * 256);
      o6 += 32768; s6a = *(const bf16x8*)(tb + o6); s6b = *(const bf16x8*)(tb + o6 + 1024);
      COMPUTE(s7a, s7b, dl + 7 * 256);
      o7 += 32768; s7a = *(const bf16x8*)(tb + o7); s7b = *(const bf16x8*)(tb + o7 + 1024);
      dl += 8 * 256;
    }
    // tail: leaves 248..255, no further issues
    COMPUTE(s0a, s0b, dl + 0 * 256);
    COMPUTE(s1a, s1b, dl + 1 * 256);
    COMPUTE(s2a, s2b, dl + 2 * 256);
    COMPUTE(s3a, s3b, dl + 3 * 256);
    COMPUTE(s4a, s4b, dl + 4 * 256);
    COMPUTE(s5a, s5b, dl + 5 * 256);
    COMPUTE(s6a, s6b, dl + 6 * 256);
    COMPUTE(s7a, s7b, dl + 7 * 256);
  } else {
    const int wB = cg * 16 + ln;
    for (int l = 0; l < NLEAF; ++l) {
      const float* tp0 = (const float*)tsrc + (size_t)l * 2048 + (g * 8) * 32 + wB;
      const float* tp1 = tp0 + 32 * 32;
      bf16x8 b0, b1;
#pragma unroll
      for (int j = 0; j < 8; ++j) {
        b0[j] = (__bf16)tp0[j * 32];
        b1[j] = (__bf16)tp1[j * 32];
      }
      COMPUTE(b0, b1, dB + l * 256);
    }
  }
#undef COMPUTE

  // ---- epilogue: C/D layout col=lane&15, row=(lane>>4)*4+reg ----
#pragma unroll
  for (int e = 0; e < 4; ++e) {
    int row = row0 + rg * 32 + g * 4 + e;
    out[(size_t)row * 32 + cg * 16 + ln] = acc0[e];
    out[(size_t)(row + 16) * 32 + cg * 16 + ln] = acc1[e];
  }
}

extern "C" void kernel_launch(void* const* d_in, const int* in_sizes, int n_in,
                              void* d_out, int out_size, void* d_ws, size_t ws_size,
                              hipStream_t stream) {
  const float* x = (const float*)d_in[0];
  const float* ray = (const float*)d_in[1];
  const float* T = (const float*)d_in[2];
  const float* w_i = (const float*)d_in[3];
  const float* b_i = (const float*)d_in[4];
  const float* a_i = (const float*)d_in[5];
  float* out = (float*)d_out;

  const int nblk = 65536 / MBLK;  // 512
  bool use_ws = ws_size >= (size_t)NLEAF * 4096;
  if (use_ws) {
    hipFuncSetAttribute(reinterpret_cast<const void*>(&prl_main<true>),
                        hipFuncAttributeMaxDynamicSharedMemorySize, SMEM_BYTES);
    prep_T<<<256, 256, 0, stream>>>(T, (__bf16*)d_ws);
    prl_main<true><<<nblk, THREADS, SMEM_BYTES, stream>>>(x, ray, w_i, b_i, a_i, d_ws, out);
  } else {
    hipFuncSetAttribute(reinterpret_cast<const void*>(&prl_main<false>),
                        hipFuncAttributeMaxDynamicSharedMemorySize, SMEM_BYTES);
    prl_main<false><<<nblk, THREADS, SMEM_BYTES, stream>>>(x, ray, w_i, b_i, a_i, T, out);
  }
}

// Round 12
// 157.326 us; speedup vs baseline: 1.3350x; 1.3350x over previous
//
#include <hip/hip_runtime.h>
#include <hip/hip_bf16.h>

#define NLEAF 256
#define MBLK 128
#define THREADS 256

typedef __attribute__((ext_vector_type(4))) float f32x4;
typedef __attribute__((ext_vector_type(4))) unsigned int uint4v;
typedef __attribute__((ext_vector_type(8))) __bf16 bf16x8;
typedef __attribute__((ext_vector_type(4))) __bf16 bf16x4;

// LDS layout (bytes), per block = 76544 B -> 2 blocks/CU
#define OFF_DIST 0      // 65536: dist bf16 [256 leaves][128 perm-rows]; first 32KB doubles as x-stage
#define OFF_T    65536  // 8192 : tree ping-pong PA/PB
#define OFF_AC   73728  // 1024 : A_c[255]
#define OFF_BC   74752  // 1024 : B_c[255]
#define OFF_ANG  75776  // 512  : angles[128]
#define OFF_RAY  76288  // 256  : ray[64]
#define SMEM_BYTES 76544

__device__ __forceinline__ float sigf(float s) { return 1.0f / (1.0f + __expf(-s)); }

// dist row permutation. row r = rg[6] mt[5:4] g[3:2] e[1:0] -> p = rg g mt e,
// so one ds_read_b128 at perm (rg*64 + g*16) delivers [mt0 e0..3 | mt1 e0..3]
// and +8 delivers [mt2 | mt3].
__device__ __forceinline__ int permr(int r) {
  return (r & 0x43) | ((r & 0x0C) << 2) | ((r & 0x30) >> 2);
}

// Pre-pass: T fp32 [l][k(64)][w(32)] -> bf16 ws in cg-major MFMA FRAGMENT ORDER:
// off(k,w) = (w>>4)*2048 + (k>>5)*1024 + (((k>>3)&3)*16 + (w&15))*16 + (k&7)*2
// so a wave (cg) reads leaf l's two fragments at l*4096 + cg*2048 + {0,1024} + lane*16.
__global__ __launch_bounds__(256) void prep_T(const float* __restrict__ T,
                                              __bf16* __restrict__ wsT) {
  __shared__ char tile[4096];
  const int l = blockIdx.x;
  const float* src = T + (size_t)l * 2048;
  const int t = threadIdx.x;
#pragma unroll
  for (int p = 0; p < 2; ++p) {
    int e = p * 1024 + t * 4;  // element within leaf: k = e>>5, w = e&31
    f32x4 v = *(const f32x4*)(src + e);
    int k = e >> 5, w0 = e & 31;
#pragma unroll
    for (int j = 0; j < 4; ++j) {
      int w = w0 + j;
      int off = (w >> 4) * 2048 + (k >> 5) * 1024 +
                (((k >> 3) & 3) * 16 + (w & 15)) * 16 + (k & 7) * 2;
      *(__bf16*)(tile + off) = (__bf16)v[j];
    }
  }
  __syncthreads();
  *(uint4v*)((char*)wsT + (size_t)l * 4096 + t * 16) = *(const uint4v*)(tile + t * 16);
}

template <bool USE_WS>
__global__ __launch_bounds__(THREADS, 2)
void prl_main(const float* __restrict__ x, const float* __restrict__ ray,
              const float* __restrict__ w_i, const float* __restrict__ b_i,
              const float* __restrict__ a_i, const void* __restrict__ tsrc,
              float* __restrict__ out) {
  extern __shared__ char smem[];
  const int tid = threadIdx.x;
  const int lane = tid & 63;
  const int wid = tid >> 6;   // 4 waves
  const int rg = wid >> 1;    // row-group: 64 rows
  const int cg = wid & 1;     // col-group: 16 cols
  const int g = lane >> 4;
  const int ln = lane & 15;
  const int row0 = blockIdx.x * MBLK;

  float* A_c = (float*)(smem + OFF_AC);
  float* B_c = (float*)(smem + OFF_BC);
  float* angles = (float*)(smem + OFF_ANG);
  float* ray_l = (float*)(smem + OFF_RAY);
  __bf16* distb = (__bf16*)(smem + OFF_DIST);

  // ---- stage node constants + ray ----
  if (tid < 255) {
    float aa = 1.0f + a_i[tid];
    A_c[tid] = (0.5f + sigf(w_i[tid])) * aa;
    B_c[tid] = -sigf(b_i[tid]) * aa;
  }
  if (tid < 64) ray_l[tid] = ray[tid];
  __syncthreads();

  // ---- ray norm (row-invariant): one 16-lane-group reduce, hoisted ----
  float rn;
  {
    f32x4 rv = *(const f32x4*)(ray_l + (tid & 15) * 4);
    float a2 = rv[0] * rv[0] + rv[1] * rv[1] + rv[2] * rv[2] + rv[3] * rv[3];
#pragma unroll
    for (int s = 1; s < 16; s <<= 1) a2 += __shfl_xor(a2, s, 64);
    rn = fmaxf(sqrtf(a2), 1e-8f);
  }

  // ---- x staging (128 rows = 32KB in dist region), angles ----
  float* xp = (float*)(smem + OFF_DIST);
  {
    const float* xg = x + (size_t)row0 * 64;
#pragma unroll
    for (int p = 0; p < 8; ++p) {
      int idx = p * 256 + tid;  // float4 slot 0..2047
      f32x4 v = *(const f32x4*)(xg + idx * 4);
      *(f32x4*)(xp + idx * 4) = v;
      int cgr = idx & 15;
      f32x4 rv = *(const f32x4*)(ray_l + cgr * 4);
      float a0 = v[0] * v[0] + v[1] * v[1] + v[2] * v[2] + v[3] * v[3];
      float a1 = v[0] * rv[0] + v[1] * rv[1] + v[2] * rv[2] + v[3] * rv[3];
#pragma unroll
      for (int s = 1; s < 16; s <<= 1) {
        a0 += __shfl_xor(a0, s, 64);
        a1 += __shfl_xor(a1, s, 64);
      }
      if ((tid & 15) == 0) {
        int r = idx >> 4;  // 0..127
        float xn = fmaxf(sqrtf(a0), 1e-8f);
        float cs = a1 / (xn * rn);
        cs = fminf(fmaxf(cs, -1.0f), 1.0f);
        angles[r] = acosf(cs) * 0.31830988618379067f;
      }
    }
  }
  __syncthreads();

  // ---- A-fragment extraction (each wave: its rg's 64 rows, both kt) ----
  bf16x8 afrag[4][2];
#pragma unroll
  for (int mt = 0; mt < 4; ++mt)
#pragma unroll
    for (int kt = 0; kt < 2; ++kt) {
      int rl = rg * 64 + mt * 16 + ln;
      int k0 = kt * 32 + g * 8;
      f32x4 u0 = *(const f32x4*)(xp + rl * 64 + k0);
      f32x4 u1 = *(const f32x4*)(xp + rl * 64 + k0 + 4);
      bf16x8 af;
      af[0] = (__bf16)u0[0]; af[1] = (__bf16)u0[1];
      af[2] = (__bf16)u0[2]; af[3] = (__bf16)u0[3];
      af[4] = (__bf16)u1[0]; af[5] = (__bf16)u1[1];
      af[6] = (__bf16)u1[2]; af[7] = (__bf16)u1[3];
      afrag[mt][kt] = af;
    }
  __syncthreads();  // x region free -> tree may overwrite with dist

  // ---- tree probabilities: ping-pong in OFF_T area (8KB), rows=128 ----
  __bf16* PA = (__bf16*)(smem + OFF_T);
  __bf16* PB = (__bf16*)(smem + OFF_T + 4096);
  if (tid < 128) {  // P0 -> P1 (2 x 128)
    float ang = angles[tid];
    float d = sigf(fmaf(A_c[0], ang, B_c[0]));
    PA[tid] = (__bf16)d;
    PA[128 + tid] = (__bf16)(1.0f - d);
  }
  __syncthreads();
  {  // P1 -> P2 (4 x 128): 256 inputs
    int n = tid >> 7, r = tid & 127;
    float p = (float)PA[tid];
    float ang = angles[r];
    float d = sigf(fmaf(A_c[1 + n], ang, B_c[1 + n]));
    PB[(2 * n) * 128 + r] = (__bf16)(p * d);
    PB[(2 * n + 1) * 128 + r] = (__bf16)(p * (1.0f - d));
  }
  __syncthreads();
#pragma unroll
  for (int it = 0; it < 2; ++it) {  // P2 -> P3 (8 x 128): 512 inputs
    int e = it * 256 + tid;
    int n = e >> 7, r = e & 127;
    float p = (float)PB[e];
    float ang = angles[r];
    float d = sigf(fmaf(A_c[3 + n], ang, B_c[3 + n]));
    PA[(2 * n) * 128 + r] = (__bf16)(p * d);
    PA[(2 * n + 1) * 128 + r] = (__bf16)(p * (1.0f - d));
  }
  __syncthreads();
#pragma unroll
  for (int it = 0; it < 4; ++it) {  // P3 -> P4 (16 x 128): 1024 inputs
    int e = it * 256 + tid;
    int n = e >> 7, r = e & 127;
    float p = (float)PA[e];
    float ang = angles[r];
    float d = sigf(fmaf(A_c[7 + n], ang, B_c[7 + n]));
    PB[(2 * n) * 128 + r] = (__bf16)(p * d);
    PB[(2 * n + 1) * 128 + r] = (__bf16)(p * (1.0f - d));
  }
  __syncthreads();
  {  // P4 -> fused levels 4..7 -> dist [leaf][perm-row]
    const int r = tid & 127;
    const int pr = permr(r);
    const float ang = angles[r];
#pragma unroll
    for (int it = 0; it < 8; ++it) {
      int n4 = it * 2 + (tid >> 7);
      float p4 = (float)PB[n4 * 128 + r];
      float d4 = sigf(fmaf(A_c[15 + n4], ang, B_c[15 + n4]));
      float p5[2] = {p4 * d4, p4 * (1.0f - d4)};
#pragma unroll
      for (int b5 = 0; b5 < 2; ++b5) {
        int n5 = 2 * n4 + b5;
        float d5 = sigf(fmaf(A_c[31 + n5], ang, B_c[31 + n5]));
        float p6[2] = {p5[b5] * d5, p5[b5] * (1.0f - d5)};
#pragma unroll
        for (int b6 = 0; b6 < 2; ++b6) {
          int n6 = 2 * n5 + b6;
          float d6 = sigf(fmaf(A_c[63 + n6], ang, B_c[63 + n6]));
          float p7[2] = {p6[b6] * d6, p6[b6] * (1.0f - d6)};
#pragma unroll
          for (int b7 = 0; b7 < 2; ++b7) {
            int n7 = 2 * n6 + b7;
            float d7 = sigf(fmaf(A_c[127 + n7], ang, B_c[127 + n7]));
            float pv = p7[b7];
            distb[(2 * n7) * 128 + pr] = (__bf16)(pv * d7);
            distb[(2 * n7 + 1) * 128 + pr] = (__bf16)(pv * (1.0f - d7));
          }
        }
      }
    }
  }
  __syncthreads();  // dist visible; NO barriers from here on — waves free-run

  // ---- leaf loop: wave = 64 rows x 16 cols. B direct global->VGPR,
  //      4 named register sets (no spill), prefetch distance ~3 phases ----
  f32x4 acc0 = {}, acc1 = {}, acc2 = {}, acc3 = {};
  const f32x4 zero = {0.0f, 0.0f, 0.0f, 0.0f};
  const char* dB = (const char*)distb + (rg * 64 + g * 16) * 2;

#define COMPUTE(BA, BB, DP)                                                        \
  {                                                                                \
    bf16x8 q0 = *(const bf16x8*)(DP);                                              \
    bf16x8 q1 = *(const bf16x8*)((DP) + 16);                                       \
    f32x4 dv0 = (f32x4){(float)q0[0], (float)q0[1], (float)q0[2], (float)q0[3]};   \
    f32x4 dv1 = (f32x4){(float)q0[4], (float)q0[5], (float)q0[6], (float)q0[7]};   \
    f32x4 dv2 = (f32x4){(float)q1[0], (float)q1[1], (float)q1[2], (float)q1[3]};   \
    f32x4 dv3 = (f32x4){(float)q1[4], (float)q1[5], (float)q1[6], (float)q1[7]};   \
    f32x4 y0 = __builtin_amdgcn_mfma_f32_16x16x32_bf16(afrag[0][0], BA, zero, 0, 0, 0); \
    y0 = __builtin_amdgcn_mfma_f32_16x16x32_bf16(afrag[0][1], BB, y0, 0, 0, 0);    \
    acc0 += dv0 * y0;                                                              \
    f32x4 y1 = __builtin_amdgcn_mfma_f32_16x16x32_bf16(afrag[1][0], BA, zero, 0, 0, 0); \
    y1 = __builtin_amdgcn_mfma_f32_16x16x32_bf16(afrag[1][1], BB, y1, 0, 0, 0);    \
    acc1 += dv1 * y1;                                                              \
    f32x4 y2 = __builtin_amdgcn_mfma_f32_16x16x32_bf16(afrag[2][0], BA, zero, 0, 0, 0); \
    y2 = __builtin_amdgcn_mfma_f32_16x16x32_bf16(afrag[2][1], BB, y2, 0, 0, 0);    \
    acc2 += dv2 * y2;                                                              \
    f32x4 y3 = __builtin_amdgcn_mfma_f32_16x16x32_bf16(afrag[3][0], BA, zero, 0, 0, 0); \
    y3 = __builtin_amdgcn_mfma_f32_16x16x32_bf16(afrag[3][1], BB, y3, 0, 0, 0);    \
    acc3 += dv3 * y3;                                                              \
  }

  if constexpr (USE_WS) {
    const char* tb = (const char*)tsrc;
    const unsigned int lo = cg * 2048 + lane * 16;
    unsigned int o0 = lo, o1 = lo + 4096, o2 = lo + 8192, o3 = lo + 12288;
    bf16x8 s0a = *(const bf16x8*)(tb + o0), s0b = *(const bf16x8*)(tb + o0 + 1024);
    bf16x8 s1a = *(const bf16x8*)(tb + o1), s1b = *(const bf16x8*)(tb + o1 + 1024);
    bf16x8 s2a = *(const bf16x8*)(tb + o2), s2b = *(const bf16x8*)(tb + o2 + 1024);
    bf16x8 s3a = *(const bf16x8*)(tb + o3), s3b = *(const bf16x8*)(tb + o3 + 1024);
    const char* dl = dB;
    for (int l4 = 0; l4 < NLEAF - 4; l4 += 4) {
      COMPUTE(s0a, s0b, dl + 0 * 256);
      o0 += 16384; s0a = *(const bf16x8*)(tb + o0); s0b = *(const bf16x8*)(tb + o0 + 1024);
      COMPUTE(s1a, s1b, dl + 1 * 256);
      o1 += 16384; s1a = *(const bf16x8*)(tb + o1); s1b = *(const bf16x8*)(tb + o1 + 1024);
      COMPUTE(s2a, s2b, dl + 2 * 256);
      o2 += 16384; s2a = *(const bf16x8*)(tb + o2); s2b = *(const bf16x8*)(tb + o2 + 1024);
      COMPUTE(s3a, s3b, dl + 3 * 256);
      o3 += 16384; s3a = *(const bf16x8*)(tb + o3); s3b = *(const bf16x8*)(tb + o3 + 1024);
      dl += 4 * 256;
    }
    // tail: leaves 252..255 already in registers
    COMPUTE(s0a, s0b, dl + 0 * 256);
    COMPUTE(s1a, s1b, dl + 1 * 256);
    COMPUTE(s2a, s2b, dl + 2 * 256);
    COMPUTE(s3a, s3b, dl + 3 * 256);
  } else {
    const int wB = cg * 16 + ln;
    for (int l = 0; l < NLEAF; ++l) {
      const float* tp0 = (const float*)tsrc + (size_t)l * 2048 + (g * 8) * 32 + wB;
      const float* tp1 = tp0 + 32 * 32;
      bf16x8 b0, b1;
#pragma unroll
      for (int j = 0; j < 8; ++j) {
        b0[j] = (__bf16)tp0[j * 32];
        b1[j] = (__bf16)tp1[j * 32];
      }
      COMPUTE(b0, b1, dB + l * 256);
    }
  }
#undef COMPUTE

  // ---- epilogue: C/D layout col=lane&15, row=(lane>>4)*4+reg ----
#pragma unroll
  for (int e = 0; e < 4; ++e) {
    int row = row0 + rg * 64 + g * 4 + e;
    int col = cg * 16 + ln;
    out[(size_t)row * 32 + col] = acc0[e];
    out[(size_t)(row + 16) * 32 + col] = acc1[e];
    out[(size_t)(row + 32) * 32 + col] = acc2[e];
    out[(size_t)(row + 48) * 32 + col] = acc3[e];
  }
}

extern "C" void kernel_launch(void* const* d_in, const int* in_sizes, int n_in,
                              void* d_out, int out_size, void* d_ws, size_t ws_size,
                              hipStream_t stream) {
  const float* x = (const float*)d_in[0];
  const float* ray = (const float*)d_in[1];
  const float* T = (const float*)d_in[2];
  const float* w_i = (const float*)d_in[3];
  const float* b_i = (const float*)d_in[4];
  const float* a_i = (const float*)d_in[5];
  float* out = (float*)d_out;

  const int nblk = 65536 / MBLK;  // 512
  bool use_ws = ws_size >= (size_t)NLEAF * 4096;
  if (use_ws) {
    hipFuncSetAttribute(reinterpret_cast<const void*>(&prl_main<true>),
                        hipFuncAttributeMaxDynamicSharedMemorySize, SMEM_BYTES);
    prep_T<<<256, 256, 0, stream>>>(T, (__bf16*)d_ws);
    prl_main<true><<<nblk, THREADS, SMEM_BYTES, stream>>>(x, ray, w_i, b_i, a_i, d_ws, out);
  } else {
    hipFuncSetAttribute(reinterpret_cast<const void*>(&prl_main<false>),
                        hipFuncAttributeMaxDynamicSharedMemorySize, SMEM_BYTES);
    prl_main<false><<<nblk, THREADS, SMEM_BYTES, stream>>>(x, ray, w_i, b_i, a_i, T, out);
  }
}